// Round 1
// baseline (1404.910 us; speedup 1.0000x reference)
//
#include <hip/hip_runtime.h>
#include <hip/hip_bf16.h>

// Problem constants (fixed by the reference)
#define ASPECTS 16
#define ADIM    128
#define KDIM    128
#define HIDDEN  2048   // ASPECTS*ADIM

// ---------------------------------------------------------------------------
// prep: wb_t[d][a] = sum_j w_b[d][j] * team[a*128+j]
//       wt_t[k][a] = sum_j w_t[k][j] * team[a*128+j]
// grid 16 (a), block 128 (row index)
// ---------------------------------------------------------------------------
__global__ void prep_kernel(const float* __restrict__ team,
                            const float* __restrict__ w_b,
                            const float* __restrict__ w_t,
                            float* __restrict__ wbt,   // [128][16]
                            float* __restrict__ wtt) { // [128][16]
    int a = blockIdx.x;
    int i = threadIdx.x;
    __shared__ float ta[ADIM];
    ta[i] = team[a * ADIM + i];
    __syncthreads();
    const float* wbr = w_b + i * ADIM;
    const float* wtr = w_t + i * ADIM;
    float s1 = 0.f, s2 = 0.f;
#pragma unroll 4
    for (int j = 0; j < ADIM; ++j) {
        s1 += wbr[j] * ta[j];
        s2 += wtr[j] * ta[j];
    }
    wbt[i * ASPECTS + a] = s1;
    wtt[i * ASPECTS + a] = s2;
}

// ---------------------------------------------------------------------------
// main: one block per node, 256 threads
// ---------------------------------------------------------------------------
__global__ __launch_bounds__(256, 4)
void coattn_main(const float* __restrict__ player,  // [N][2048]
                 const float* __restrict__ w_p,     // [128][128]
                 const float* __restrict__ wbt,     // [128][16]
                 const float* __restrict__ wtt,     // [128][16]
                 const float* __restrict__ w_ht,    // [128][16]
                 const float* __restrict__ w_hp,    // [128][16]
                 float* __restrict__ pout,          // [N][2048] (d_out+2048)
                 float* __restrict__ attsum) {      // [256][256] slot partials
    const int n   = blockIdx.x;
    const int tid = threadIdx.x;

    __shared__ float sp[ASPECTS][ADIM + 4];   // player aspects, padded
    __shared__ float C[ASPECTS][ASPECTS + 1]; // tanh(p . wb_t)
    __shared__ float wpp[KDIM][ASPECTS + 1];  // wp_p[k][a]
    __shared__ float tco[KDIM][ASPECTS + 1];  // team_co
    __shared__ float pco[KDIM][ASPECTS + 1];  // player_co
    __shared__ float att_t[ASPECTS][ASPECTS + 1];
    __shared__ float att_p[ASPECTS][ASPECTS + 1];

    // ---- Step 0: stage p[n] into LDS (coalesced float4) ----
    {
        const float4* prow = (const float4*)(player + (size_t)n * HIDDEN);
#pragma unroll
        for (int v = 0; v < 2; ++v) {
            int idx = tid + v * 256;          // 0..511 float4s
            int a = idx >> 5;                 // 32 float4 per aspect row
            int c = idx & 31;
            float4 p4 = prow[idx];
            *(float4*)&sp[a][c * 4] = p4;
        }
    }
    __syncthreads();

    // ---- Step 1: C[a][b] = tanh( sum_d sp[a][d] * wbt[d][b] ) ----
    {
        int a = tid >> 4, b = tid & 15;
        float acc = 0.f;
#pragma unroll 4
        for (int d = 0; d < ADIM; ++d)
            acc += sp[a][d] * wbt[d * ASPECTS + b];
        C[a][b] = tanhf(acc);
    }
    __syncthreads();

    // ---- Step 2: wpp[k][a] = sum_d w_p[k][d] * sp[a][d] ----
    {
        int k = tid & 127, h = tid >> 7;      // h selects aspect half
        const float* wrow = w_p + k * ADIM;
        float acc[8] = {0.f, 0.f, 0.f, 0.f, 0.f, 0.f, 0.f, 0.f};
        for (int d = 0; d < ADIM; d += 4) {
            float4 w4 = *(const float4*)&wrow[d];
#pragma unroll
            for (int j = 0; j < 8; ++j) {
                float4 s4 = *(const float4*)&sp[h * 8 + j][d]; // wave-broadcast
                acc[j] += w4.x * s4.x + w4.y * s4.y + w4.z * s4.z + w4.w * s4.w;
            }
        }
#pragma unroll
        for (int j = 0; j < 8; ++j) wpp[k][h * 8 + j] = acc[j];
    }
    __syncthreads();

    // ---- Step 3: team_co (waves 0-1) / player_co (waves 2-3) ----
    {
        int k = tid & 127;
        if (tid < 128) {
            float wr[ASPECTS];
#pragma unroll
            for (int a = 0; a < ASPECTS; ++a) wr[a] = wpp[k][a];
#pragma unroll
            for (int b = 0; b < ASPECTS; ++b) {
                float s = wtt[k * ASPECTS + b];
#pragma unroll
                for (int a = 0; a < ASPECTS; ++a) s += wr[a] * C[a][b];
                tco[k][b] = tanhf(s);
            }
        } else {
            float wr[ASPECTS];
#pragma unroll
            for (int a = 0; a < ASPECTS; ++a) wr[a] = wtt[k * ASPECTS + a];
#pragma unroll
            for (int b = 0; b < ASPECTS; ++b) {
                float s = wpp[k][b];
#pragma unroll
                for (int a = 0; a < ASPECTS; ++a) s += wr[a] * C[b][a];
                pco[k][b] = tanhf(s);
            }
        }
    }
    __syncthreads();

    // ---- Step 4: scores + softmax over b ----
    {
        int a = tid >> 4, b = tid & 15;
        float st = 0.f, spv = 0.f;
#pragma unroll 4
        for (int k = 0; k < KDIM; ++k) {
            st  += w_ht[k * ASPECTS + a] * tco[k][b];
            spv += w_hp[k * ASPECTS + a] * pco[k][b];
        }
        att_t[a][b] = st;
        att_p[a][b] = spv;
        __syncthreads();
        float mt = -1e30f, mp = -1e30f;
#pragma unroll
        for (int j = 0; j < ASPECTS; ++j) {
            mt = fmaxf(mt, att_t[a][j]);
            mp = fmaxf(mp, att_p[a][j]);
        }
        float et = __expf(st - mt), ep = __expf(spv - mp);
        __syncthreads();
        att_t[a][b] = et;
        att_p[a][b] = ep;
        __syncthreads();
        float dt = 0.f, dp = 0.f;
#pragma unroll
        for (int j = 0; j < ASPECTS; ++j) {
            dt += att_t[a][j];
            dp += att_p[a][j];
        }
        et /= dt;
        ep /= dp;
        __syncthreads();
        att_t[a][b] = et;
        att_p[a][b] = ep;
        // team_out mean only needs sum_n att_t: slot-strided partials
        atomicAdd(&attsum[(blockIdx.x & 255) * 256 + tid], et);
    }
    __syncthreads();

    // ---- Step 5: player_out[a][d] = sum_b att_p[a][b] * sp[b][d] ----
    {
        int a = tid >> 4, c = tid & 15;
        float4 o0 = {0.f, 0.f, 0.f, 0.f}, o1 = {0.f, 0.f, 0.f, 0.f};
#pragma unroll
        for (int b = 0; b < ASPECTS; ++b) {
            float w = att_p[a][b];
            float4 s0 = *(const float4*)&sp[b][c * 4];
            float4 s1 = *(const float4*)&sp[b][c * 4 + 64];
            o0.x += w * s0.x; o0.y += w * s0.y; o0.z += w * s0.z; o0.w += w * s0.w;
            o1.x += w * s1.x; o1.y += w * s1.y; o1.z += w * s1.z; o1.w += w * s1.w;
        }
        float* orow = pout + (size_t)n * HIDDEN + a * ADIM;
        *(float4*)&orow[c * 4]      = o0;
        *(float4*)&orow[c * 4 + 64] = o1;
    }
}

// ---------------------------------------------------------------------------
// epilogue: out0[a][d] = (1/N) * sum_b (sum_n att_t[n][a][b]) * team[b*128+d]
// grid 16 (a), block 128 (d)
// ---------------------------------------------------------------------------
__global__ void epi_kernel(const float* __restrict__ team,
                           const float* __restrict__ attsum,
                           float* __restrict__ out0, float inv_n) {
    int a = blockIdx.x;
    int tid = threadIdx.x;
    __shared__ float ab[ASPECTS];
    if (tid < ASPECTS) {
        float s = 0.f;
        for (int slot = 0; slot < 256; ++slot)
            s += attsum[slot * 256 + a * ASPECTS + tid];
        ab[tid] = s * inv_n;
    }
    __syncthreads();
    float o = 0.f;
#pragma unroll
    for (int b = 0; b < ASPECTS; ++b)
        o += ab[b] * team[b * ADIM + tid];
    out0[a * ADIM + tid] = o;
}

extern "C" void kernel_launch(void* const* d_in, const int* in_sizes, int n_in,
                              void* d_out, int out_size, void* d_ws, size_t ws_size,
                              hipStream_t stream) {
    const float* team   = (const float*)d_in[0];
    const float* player = (const float*)d_in[1];
    const float* w_b    = (const float*)d_in[2];
    const float* w_t    = (const float*)d_in[3];
    const float* w_p    = (const float*)d_in[4];
    const float* w_ht   = (const float*)d_in[5];
    const float* w_hp   = (const float*)d_in[6];
    float* out = (float*)d_out;

    int n = in_sizes[1] / HIDDEN;   // 32768

    float* wbt    = (float*)d_ws;          // 2048 floats
    float* wtt    = wbt + 2048;            // 2048 floats
    float* attsum = wtt + 2048;            // 65536 floats

    hipMemsetAsync(attsum, 0, 256 * 256 * sizeof(float), stream);
    prep_kernel<<<ASPECTS, ADIM, 0, stream>>>(team, w_b, w_t, wbt, wtt);
    coattn_main<<<n, 256, 0, stream>>>(player, w_p, wbt, wtt, w_ht, w_hp,
                                       out + HIDDEN, attsum);
    epi_kernel<<<ASPECTS, ADIM, 0, stream>>>(team, attsum, out, 1.0f / (float)n);
}